// Round 5
// baseline (361.868 us; speedup 1.0000x reference)
//
#include <hip/hip_runtime.h>
#include <math.h>

// GCN 2-layer, N=100000, E=6400000, Fin=1, Fhid=16, Fout=2.
// R5: hierarchical. Counting-sort edges into 98 COARSE buckets (1024 dst-nodes
// each) -> k_place write runs are ~1KB, killing R4's 5x write amplification
// (125MB -> ~28MB). Aggregation (deg / layer1 / layer2) uses per-block LDS
// accumulators covering a whole 1024-node bucket (4-8KB static LDS), with each
// bucket's contiguous edge range split over S=4 blocks writing partials;
// a cheap node pass sums the 4 partials. No global atomics anywhere.
// packed word = (dst & 1023) << 17 | src   (src < 2^17).

#define CSH   10
#define CMASK 1023
#define C     1024
#define B1    256      // sort blocks; chunk = E/B1 = 25000 (exact, /4 exact)
#define S     4        // splits per bucket in aggregation
#define SCAN_T 512

// --- histogram of dst>>10 per block-chunk (per-wave sub-hist, low contention)
__global__ __launch_bounds__(256) void k_hist(const int* __restrict__ dst,
                                              int* __restrict__ G,
                                              int chunk, int nbkt) {
    __shared__ int sh[512];   // 4 waves x 128 counters
    int t = threadIdx.x, blk = blockIdx.x;
    sh[t] = 0; sh[t + 256] = 0;
    __syncthreads();
    int w = (t >> 6) << 7;    // wave * 128
    const int4* d4 = (const int4*)(dst + blk * chunk);
    int n4 = chunk >> 2;
    for (int i = t; i < n4; i += 256) {
        int4 d = d4[i];
        atomicAdd(&sh[w + (d.x >> CSH)], 1);
        atomicAdd(&sh[w + (d.y >> CSH)], 1);
        atomicAdd(&sh[w + (d.z >> CSH)], 1);
        atomicAdd(&sh[w + (d.w >> CSH)], 1);
    }
    __syncthreads();
    if (t < nbkt)
        G[t * B1 + blk] = sh[t] + sh[128 + t] + sh[256 + t] + sh[384 + t];
}

// --- single-block exclusive scan over G[NP] (bucket-major), proven in R2/R4
__global__ __launch_bounds__(SCAN_T) void k_scan(int* __restrict__ G, int NP) {
    __shared__ int sh[SCAN_T];
    int t = threadIdx.x;
    int carry = 0;
    for (int base = 0; base < NP; base += SCAN_T) {
        int i = base + t;
        int v = (i < NP) ? G[i] : 0;
        sh[t] = v;
        __syncthreads();
        for (int off = 1; off < SCAN_T; off <<= 1) {
            int u = (t >= off) ? sh[t - off] : 0;
            __syncthreads();
            sh[t] += u;
            __syncthreads();
        }
        if (i < NP) G[i] = carry + sh[t] - v;
        carry += sh[SCAN_T - 1];
        __syncthreads();
    }
}

// --- scatter edges to bucket-sorted `packed` (LDS running offsets, 98 ctrs)
__global__ __launch_bounds__(256) void k_place(const int* __restrict__ src,
                                               const int* __restrict__ dst,
                                               const int* __restrict__ Gs,
                                               int* __restrict__ packed,
                                               int chunk, int nbkt) {
    __shared__ int offs[128];
    int t = threadIdx.x, blk = blockIdx.x;
    if (t < nbkt) offs[t] = Gs[t * B1 + blk];
    __syncthreads();
    int s0 = blk * chunk, n4 = chunk >> 2;
    const int4* d4 = (const int4*)(dst + s0);
    const int4* s4 = (const int4*)(src + s0);
    for (int i = t; i < n4; i += 256) {
        int4 d = d4[i];
        int4 s = s4[i];
        int b, p;
        b = d.x >> CSH; p = atomicAdd(&offs[b], 1); packed[p] = ((d.x & CMASK) << 17) | s.x;
        b = d.y >> CSH; p = atomicAdd(&offs[b], 1); packed[p] = ((d.y & CMASK) << 17) | s.y;
        b = d.z >> CSH; p = atomicAdd(&offs[b], 1); packed[p] = ((d.z & CMASK) << 17) | s.z;
        b = d.w >> CSH; p = atomicAdd(&offs[b], 1); packed[p] = ((d.w & CMASK) << 17) | s.w;
    }
}

// --- degree partials: block (b,s) counts its quarter of bucket b into LDS
__global__ __launch_bounds__(256) void k_deg(const int* __restrict__ packed,
                                             const int* __restrict__ Gs,
                                             int* __restrict__ Pdeg,
                                             int E, int nbkt) {
    __shared__ int cnt[C];
    int t = threadIdx.x, g = blockIdx.x;
    int b = g >> 2, s = g & 3;
    cnt[t] = 0; cnt[t + 256] = 0; cnt[t + 512] = 0; cnt[t + 768] = 0;
    __syncthreads();
    int st = Gs[b * B1];
    int en = (b == nbkt - 1) ? E : Gs[(b + 1) * B1];
    int len = en - st;
    int lo = st + ((len * s) >> 2);          // len < 2^19, no overflow
    int hi = st + ((len * (s + 1)) >> 2);
    for (int i = lo + t; i < hi; i += 256)
        atomicAdd(&cnt[packed[i] >> 17], 1);
    __syncthreads();
    int* row = Pdeg + g * C;
    row[t] = cnt[t]; row[t + 256] = cnt[t + 256];
    row[t + 512] = cnt[t + 512]; row[t + 768] = cnt[t + 768];
}

// --- nodes: deg -> dinv, y = dinv * x
__global__ __launch_bounds__(256) void k_node1(const int* __restrict__ Pdeg,
                                               const float* __restrict__ x,
                                               float* __restrict__ dinv,
                                               float* __restrict__ y, int N) {
    int node = blockIdx.x * 256 + threadIdx.x;
    if (node >= N) return;
    int b = node >> CSH, l = node & CMASK;
    const int* base = Pdeg + (b * S) * C + l;
    int deg = base[0] + base[C] + base[2 * C] + base[3 * C];
    float di = rsqrtf((float)deg + 1.0f);   // +1 self-loop
    dinv[node] = di;
    y[node] = di * x[node];
}

// --- layer-1 partials: sum y[src] per dst-local
__global__ __launch_bounds__(256) void k_agg1(const int* __restrict__ packed,
                                              const int* __restrict__ Gs,
                                              const float* __restrict__ y,
                                              float* __restrict__ P1,
                                              int E, int nbkt) {
    __shared__ float acc[C];
    int t = threadIdx.x, g = blockIdx.x;
    int b = g >> 2, s = g & 3;
    acc[t] = 0.f; acc[t + 256] = 0.f; acc[t + 512] = 0.f; acc[t + 768] = 0.f;
    __syncthreads();
    int st = Gs[b * B1];
    int en = (b == nbkt - 1) ? E : Gs[(b + 1) * B1];
    int len = en - st;
    int lo = st + ((len * s) >> 2);
    int hi = st + ((len * (s + 1)) >> 2);
    for (int i = lo + t; i < hi; i += 256) {
        int p = packed[i];
        atomicAdd(&acc[p >> 17], y[p & 0x1FFFF]);
    }
    __syncthreads();
    float* row = P1 + g * C;
    row[t] = acc[t]; row[t + 256] = acc[t + 256];
    row[t + 512] = acc[t + 512]; row[t + 768] = acc[t + 768];
}

// --- nodes: S1 = dinv*(sum + y), fused 1->16 relu MLP -> 16->2, premul dinv
__global__ __launch_bounds__(256) void k_node2(const float* __restrict__ P1,
                                               const float* __restrict__ dinv,
                                               const float* __restrict__ y,
                                               const float* __restrict__ W1,
                                               const float* __restrict__ b1,
                                               const float* __restrict__ W2,
                                               float2* __restrict__ gy, int N) {
    int node = blockIdx.x * 256 + threadIdx.x;
    if (node >= N) return;
    int b = node >> CSH, l = node & CMASK;
    const float* base = P1 + (b * S) * C + l;
    float sum = base[0] + base[C] + base[2 * C] + base[3 * C];
    float di = dinv[node];
    float Sv = di * (sum + y[node]);        // self-loop adds y[node]
    float g0 = 0.f, g1 = 0.f;
#pragma unroll
    for (int f = 0; f < 16; f++) {
        float h = fmaxf(fmaf(W1[f], Sv, b1[f]), 0.f);
        g0 = fmaf(h, W2[2 * f], g0);
        g1 = fmaf(h, W2[2 * f + 1], g1);
    }
    gy[node] = make_float2(di * g0, di * g1);  // premultiplied by dinv[src]
}

// --- layer-2 partials: sum gy[src] (2 floats) per dst-local
__global__ __launch_bounds__(256) void k_agg2(const int* __restrict__ packed,
                                              const int* __restrict__ Gs,
                                              const float2* __restrict__ gy,
                                              float* __restrict__ P2,
                                              int E, int nbkt) {
    __shared__ float a0[C];
    __shared__ float a1[C];
    int t = threadIdx.x, g = blockIdx.x;
    int b = g >> 2, s = g & 3;
#pragma unroll
    for (int k = 0; k < 4; k++) { a0[t + 256 * k] = 0.f; a1[t + 256 * k] = 0.f; }
    __syncthreads();
    int st = Gs[b * B1];
    int en = (b == nbkt - 1) ? E : Gs[(b + 1) * B1];
    int len = en - st;
    int lo = st + ((len * s) >> 2);
    int hi = st + ((len * (s + 1)) >> 2);
    for (int i = lo + t; i < hi; i += 256) {
        int p = packed[i];
        float2 v = gy[p & 0x1FFFF];
        int l = p >> 17;
        atomicAdd(&a0[l], v.x);
        atomicAdd(&a1[l], v.y);
    }
    __syncthreads();
    float* row = P2 + (size_t)g * 2 * C;
#pragma unroll
    for (int k = 0; k < 4; k++) {
        row[t + 256 * k] = a0[t + 256 * k];
        row[C + t + 256 * k] = a1[t + 256 * k];
    }
}

// --- nodes: sum partials, + self-loop, bias, log_softmax
__global__ __launch_bounds__(256) void k_node3(const float* __restrict__ P2,
                                               const float* __restrict__ dinv,
                                               const float2* __restrict__ gy,
                                               const float* __restrict__ b2,
                                               float2* __restrict__ out, int N) {
    int node = blockIdx.x * 256 + threadIdx.x;
    if (node >= N) return;
    int b = node >> CSH, l = node & CMASK;
    const float* base = P2 + (size_t)(b * S) * 2 * C + l;
    float t0 = base[0] + base[2 * C] + base[4 * C] + base[6 * C];
    float t1 = base[C] + base[3 * C] + base[5 * C] + base[7 * C];
    float di = dinv[node];
    float2 g = gy[node];
    float z0 = di * (t0 + g.x) + b2[0];
    float z1 = di * (t1 + g.y) + b2[1];
    float m = fmaxf(z0, z1);
    float lse = logf(expf(z0 - m) + expf(z1 - m));
    out[node] = make_float2(z0 - m - lse, z1 - m - lse);
}

extern "C" void kernel_launch(void* const* d_in, const int* in_sizes, int n_in,
                              void* d_out, int out_size, void* d_ws, size_t ws_size,
                              hipStream_t stream) {
    const float* x  = (const float*)d_in[0];
    const int* ei   = (const int*)d_in[1];
    const float* W1 = (const float*)d_in[2];
    const float* b1 = (const float*)d_in[3];
    const float* W2 = (const float*)d_in[4];
    const float* b2 = (const float*)d_in[5];

    const int N = in_sizes[0];        // 100000
    const int E = in_sizes[1] / 2;    // 6400000
    const int* src = ei;
    const int* dst = ei + E;

    const int nbkt  = (N + CMASK) >> CSH;    // 98
    const int chunk = E / B1;                // 25000 (exact; /4 exact)
    const int NP    = nbkt * B1;             // 25088
    const int gAgg  = nbkt * S;              // 392

    // ws (ints): packed[E] | G[NP] | Pbuf[gAgg*2C] | dinv[np] | y[np] | gy[2np]
    // Pbuf is reused: Pdeg (int) -> P1 (float) -> P2 (float, full 2C rows);
    // each is fully consumed by the following node pass before the next write.
    int* packed = (int*)d_ws;
    int* G      = packed + E;
    int* Pbuf   = G + NP;
    const int np = nbkt << CSH;              // 100352
    float* dinv = (float*)(Pbuf + (size_t)gAgg * 2 * C);
    float* y    = dinv + np;
    float2* gy  = (float2*)(y + np);
    // total = 6.4M + 25088 + 802816 + 4*np ints = ~30.5 MB (<= proven R2 usage)

    const int gN = (N + 255) / 256;          // 391

    k_hist <<<B1,   256,    0, stream>>>(dst, G, chunk, nbkt);
    k_scan <<<1,    SCAN_T, 0, stream>>>(G, NP);
    k_place<<<B1,   256,    0, stream>>>(src, dst, G, packed, chunk, nbkt);
    k_deg  <<<gAgg, 256,    0, stream>>>(packed, G, Pbuf, E, nbkt);
    k_node1<<<gN,   256,    0, stream>>>(Pbuf, x, dinv, y, N);
    k_agg1 <<<gAgg, 256,    0, stream>>>(packed, G, y, (float*)Pbuf, E, nbkt);
    k_node2<<<gN,   256,    0, stream>>>((const float*)Pbuf, dinv, y, W1, b1, W2, gy, N);
    k_agg2 <<<gAgg, 256,    0, stream>>>(packed, G, gy, (float*)Pbuf, E, nbkt);
    k_node3<<<gN,   256,    0, stream>>>((const float*)Pbuf, dinv, gy, b2, (float2*)d_out, N);
}

// Round 6
// 349.779 us; speedup vs baseline: 1.0346x; 1.0346x over previous
//
#include <hip/hip_runtime.h>
#include <math.h>

// GCN 2-layer, N=100000, E=6400000, Fin=1, Fhid=16, Fout=2.
// R6 = R5 (coarse 98x1024-node bucket sort, LDS-accumulator partial
// aggregation, no global atomics) with the agg kernels de-latency-bound:
//   - 1024-thread blocks (16 waves) for k_deg/k_agg1/k_agg2 -> ~24 waves/CU
//     (R5 had ~4: grid 392 x 256 threads = 1 block/CU, Occupancy 12.9%).
//   - 4-way unrolled edge loop: 4 independent gathers in flight per thread.
// Memory layout identical to R5 (~30.5 MB, proven within ws_size).
// packed word = (dst & 1023) << 17 | src   (src < 2^17).

#define CSH   10
#define CMASK 1023
#define C     1024
#define B1    256      // sort blocks; chunk = E/B1 = 25000 (exact, /4 exact)
#define S     4        // splits per bucket in aggregation
#define SCAN_T 512
#define AT    1024     // agg block threads

// --- histogram of dst>>10 per block-chunk (per-wave sub-hist, low contention)
__global__ __launch_bounds__(256) void k_hist(const int* __restrict__ dst,
                                              int* __restrict__ G,
                                              int chunk, int nbkt) {
    __shared__ int sh[512];   // 4 waves x 128 counters
    int t = threadIdx.x, blk = blockIdx.x;
    sh[t] = 0; sh[t + 256] = 0;
    __syncthreads();
    int w = (t >> 6) << 7;    // wave * 128
    const int4* d4 = (const int4*)(dst + blk * chunk);
    int n4 = chunk >> 2;
    for (int i = t; i < n4; i += 256) {
        int4 d = d4[i];
        atomicAdd(&sh[w + (d.x >> CSH)], 1);
        atomicAdd(&sh[w + (d.y >> CSH)], 1);
        atomicAdd(&sh[w + (d.z >> CSH)], 1);
        atomicAdd(&sh[w + (d.w >> CSH)], 1);
    }
    __syncthreads();
    if (t < nbkt)
        G[t * B1 + blk] = sh[t] + sh[128 + t] + sh[256 + t] + sh[384 + t];
}

// --- single-block exclusive scan over G[NP] (bucket-major)
__global__ __launch_bounds__(SCAN_T) void k_scan(int* __restrict__ G, int NP) {
    __shared__ int sh[SCAN_T];
    int t = threadIdx.x;
    int carry = 0;
    for (int base = 0; base < NP; base += SCAN_T) {
        int i = base + t;
        int v = (i < NP) ? G[i] : 0;
        sh[t] = v;
        __syncthreads();
        for (int off = 1; off < SCAN_T; off <<= 1) {
            int u = (t >= off) ? sh[t - off] : 0;
            __syncthreads();
            sh[t] += u;
            __syncthreads();
        }
        if (i < NP) G[i] = carry + sh[t] - v;
        carry += sh[SCAN_T - 1];
        __syncthreads();
    }
}

// --- scatter edges to bucket-sorted `packed` (LDS running offsets, 98 ctrs)
__global__ __launch_bounds__(256) void k_place(const int* __restrict__ src,
                                               const int* __restrict__ dst,
                                               const int* __restrict__ Gs,
                                               int* __restrict__ packed,
                                               int chunk, int nbkt) {
    __shared__ int offs[128];
    int t = threadIdx.x, blk = blockIdx.x;
    if (t < nbkt) offs[t] = Gs[t * B1 + blk];
    __syncthreads();
    int s0 = blk * chunk, n4 = chunk >> 2;
    const int4* d4 = (const int4*)(dst + s0);
    const int4* s4 = (const int4*)(src + s0);
    for (int i = t; i < n4; i += 256) {
        int4 d = d4[i];
        int4 s = s4[i];
        int b, p;
        b = d.x >> CSH; p = atomicAdd(&offs[b], 1); packed[p] = ((d.x & CMASK) << 17) | s.x;
        b = d.y >> CSH; p = atomicAdd(&offs[b], 1); packed[p] = ((d.y & CMASK) << 17) | s.y;
        b = d.z >> CSH; p = atomicAdd(&offs[b], 1); packed[p] = ((d.z & CMASK) << 17) | s.z;
        b = d.w >> CSH; p = atomicAdd(&offs[b], 1); packed[p] = ((d.w & CMASK) << 17) | s.w;
    }
}

// --- degree partials: block (b,s) counts its quarter of bucket b into LDS
__global__ __launch_bounds__(AT) void k_deg(const int* __restrict__ packed,
                                            const int* __restrict__ Gs,
                                            int* __restrict__ Pdeg,
                                            int E, int nbkt) {
    __shared__ int cnt[C];
    int t = threadIdx.x, g = blockIdx.x;
    int b = g >> 2, s = g & 3;
    cnt[t] = 0;
    __syncthreads();
    int st = Gs[b * B1];
    int en = (b == nbkt - 1) ? E : Gs[(b + 1) * B1];
    int len = en - st;
    int lo = st + ((len * s) >> 2);          // len < 2^19, no overflow
    int hi = st + ((len * (s + 1)) >> 2);
    int i = lo + t;
    for (; i + 3 * AT < hi; i += 4 * AT) {
        int p0 = packed[i], p1 = packed[i + AT], p2 = packed[i + 2 * AT], p3 = packed[i + 3 * AT];
        atomicAdd(&cnt[p0 >> 17], 1);
        atomicAdd(&cnt[p1 >> 17], 1);
        atomicAdd(&cnt[p2 >> 17], 1);
        atomicAdd(&cnt[p3 >> 17], 1);
    }
    for (; i < hi; i += AT)
        atomicAdd(&cnt[packed[i] >> 17], 1);
    __syncthreads();
    Pdeg[g * C + t] = cnt[t];
}

// --- nodes: deg -> dinv, y = dinv * x
__global__ __launch_bounds__(256) void k_node1(const int* __restrict__ Pdeg,
                                               const float* __restrict__ x,
                                               float* __restrict__ dinv,
                                               float* __restrict__ y, int N) {
    int node = blockIdx.x * 256 + threadIdx.x;
    if (node >= N) return;
    int b = node >> CSH, l = node & CMASK;
    const int* base = Pdeg + (b * S) * C + l;
    int deg = base[0] + base[C] + base[2 * C] + base[3 * C];
    float di = rsqrtf((float)deg + 1.0f);   // +1 self-loop
    dinv[node] = di;
    y[node] = di * x[node];
}

// --- layer-1 partials: sum y[src] per dst-local
__global__ __launch_bounds__(AT) void k_agg1(const int* __restrict__ packed,
                                             const int* __restrict__ Gs,
                                             const float* __restrict__ y,
                                             float* __restrict__ P1,
                                             int E, int nbkt) {
    __shared__ float acc[C];
    int t = threadIdx.x, g = blockIdx.x;
    int b = g >> 2, s = g & 3;
    acc[t] = 0.f;
    __syncthreads();
    int st = Gs[b * B1];
    int en = (b == nbkt - 1) ? E : Gs[(b + 1) * B1];
    int len = en - st;
    int lo = st + ((len * s) >> 2);
    int hi = st + ((len * (s + 1)) >> 2);
    int i = lo + t;
    for (; i + 3 * AT < hi; i += 4 * AT) {
        int p0 = packed[i], p1 = packed[i + AT], p2 = packed[i + 2 * AT], p3 = packed[i + 3 * AT];
        float v0 = y[p0 & 0x1FFFF], v1 = y[p1 & 0x1FFFF];
        float v2 = y[p2 & 0x1FFFF], v3 = y[p3 & 0x1FFFF];
        atomicAdd(&acc[p0 >> 17], v0);
        atomicAdd(&acc[p1 >> 17], v1);
        atomicAdd(&acc[p2 >> 17], v2);
        atomicAdd(&acc[p3 >> 17], v3);
    }
    for (; i < hi; i += AT) {
        int p = packed[i];
        atomicAdd(&acc[p >> 17], y[p & 0x1FFFF]);
    }
    __syncthreads();
    P1[g * C + t] = acc[t];
}

// --- nodes: S1 = dinv*(sum + y), fused 1->16 relu MLP -> 16->2, premul dinv
__global__ __launch_bounds__(256) void k_node2(const float* __restrict__ P1,
                                               const float* __restrict__ dinv,
                                               const float* __restrict__ y,
                                               const float* __restrict__ W1,
                                               const float* __restrict__ b1,
                                               const float* __restrict__ W2,
                                               float2* __restrict__ gy, int N) {
    int node = blockIdx.x * 256 + threadIdx.x;
    if (node >= N) return;
    int b = node >> CSH, l = node & CMASK;
    const float* base = P1 + (b * S) * C + l;
    float sum = base[0] + base[C] + base[2 * C] + base[3 * C];
    float di = dinv[node];
    float Sv = di * (sum + y[node]);        // self-loop adds y[node]
    float g0 = 0.f, g1 = 0.f;
#pragma unroll
    for (int f = 0; f < 16; f++) {
        float h = fmaxf(fmaf(W1[f], Sv, b1[f]), 0.f);
        g0 = fmaf(h, W2[2 * f], g0);
        g1 = fmaf(h, W2[2 * f + 1], g1);
    }
    gy[node] = make_float2(di * g0, di * g1);  // premultiplied by dinv[src]
}

// --- layer-2 partials: sum gy[src] (2 floats) per dst-local
__global__ __launch_bounds__(AT) void k_agg2(const int* __restrict__ packed,
                                             const int* __restrict__ Gs,
                                             const float2* __restrict__ gy,
                                             float* __restrict__ P2,
                                             int E, int nbkt) {
    __shared__ float a0[C];
    __shared__ float a1[C];
    int t = threadIdx.x, g = blockIdx.x;
    int b = g >> 2, s = g & 3;
    a0[t] = 0.f; a1[t] = 0.f;
    __syncthreads();
    int st = Gs[b * B1];
    int en = (b == nbkt - 1) ? E : Gs[(b + 1) * B1];
    int len = en - st;
    int lo = st + ((len * s) >> 2);
    int hi = st + ((len * (s + 1)) >> 2);
    int i = lo + t;
    for (; i + 3 * AT < hi; i += 4 * AT) {
        int p0 = packed[i], p1 = packed[i + AT], p2 = packed[i + 2 * AT], p3 = packed[i + 3 * AT];
        float2 v0 = gy[p0 & 0x1FFFF], v1 = gy[p1 & 0x1FFFF];
        float2 v2 = gy[p2 & 0x1FFFF], v3 = gy[p3 & 0x1FFFF];
        atomicAdd(&a0[p0 >> 17], v0.x); atomicAdd(&a1[p0 >> 17], v0.y);
        atomicAdd(&a0[p1 >> 17], v1.x); atomicAdd(&a1[p1 >> 17], v1.y);
        atomicAdd(&a0[p2 >> 17], v2.x); atomicAdd(&a1[p2 >> 17], v2.y);
        atomicAdd(&a0[p3 >> 17], v3.x); atomicAdd(&a1[p3 >> 17], v3.y);
    }
    for (; i < hi; i += AT) {
        int p = packed[i];
        float2 v = gy[p & 0x1FFFF];
        atomicAdd(&a0[p >> 17], v.x);
        atomicAdd(&a1[p >> 17], v.y);
    }
    __syncthreads();
    float* row = P2 + (size_t)g * 2 * C;
    row[t] = a0[t];
    row[C + t] = a1[t];
}

// --- nodes: sum partials, + self-loop, bias, log_softmax
__global__ __launch_bounds__(256) void k_node3(const float* __restrict__ P2,
                                               const float* __restrict__ dinv,
                                               const float2* __restrict__ gy,
                                               const float* __restrict__ b2,
                                               float2* __restrict__ out, int N) {
    int node = blockIdx.x * 256 + threadIdx.x;
    if (node >= N) return;
    int b = node >> CSH, l = node & CMASK;
    const float* base = P2 + (size_t)(b * S) * 2 * C + l;
    float t0 = base[0] + base[2 * C] + base[4 * C] + base[6 * C];
    float t1 = base[C] + base[3 * C] + base[5 * C] + base[7 * C];
    float di = dinv[node];
    float2 g = gy[node];
    float z0 = di * (t0 + g.x) + b2[0];
    float z1 = di * (t1 + g.y) + b2[1];
    float m = fmaxf(z0, z1);
    float lse = logf(expf(z0 - m) + expf(z1 - m));
    out[node] = make_float2(z0 - m - lse, z1 - m - lse);
}

extern "C" void kernel_launch(void* const* d_in, const int* in_sizes, int n_in,
                              void* d_out, int out_size, void* d_ws, size_t ws_size,
                              hipStream_t stream) {
    const float* x  = (const float*)d_in[0];
    const int* ei   = (const int*)d_in[1];
    const float* W1 = (const float*)d_in[2];
    const float* b1 = (const float*)d_in[3];
    const float* W2 = (const float*)d_in[4];
    const float* b2 = (const float*)d_in[5];

    const int N = in_sizes[0];        // 100000
    const int E = in_sizes[1] / 2;    // 6400000
    const int* src = ei;
    const int* dst = ei + E;

    const int nbkt  = (N + CMASK) >> CSH;    // 98
    const int chunk = E / B1;                // 25000 (exact; /4 exact)
    const int NP    = nbkt * B1;             // 25088
    const int gAgg  = nbkt * S;              // 392

    // ws (ints): packed[E] | G[NP] | Pbuf[gAgg*2C] | dinv[np] | y[np] | gy[2np]
    // identical layout to R5 (~30.5 MB, proven within ws_size)
    int* packed = (int*)d_ws;
    int* G      = packed + E;
    int* Pbuf   = G + NP;
    const int np = nbkt << CSH;              // 100352
    float* dinv = (float*)(Pbuf + (size_t)gAgg * 2 * C);
    float* y    = dinv + np;
    float2* gy  = (float2*)(y + np);

    const int gN = (N + 255) / 256;          // 391

    k_hist <<<B1,   256,    0, stream>>>(dst, G, chunk, nbkt);
    k_scan <<<1,    SCAN_T, 0, stream>>>(G, NP);
    k_place<<<B1,   256,    0, stream>>>(src, dst, G, packed, chunk, nbkt);
    k_deg  <<<gAgg, AT,     0, stream>>>(packed, G, Pbuf, E, nbkt);
    k_node1<<<gN,   256,    0, stream>>>(Pbuf, x, dinv, y, N);
    k_agg1 <<<gAgg, AT,     0, stream>>>(packed, G, y, (float*)Pbuf, E, nbkt);
    k_node2<<<gN,   256,    0, stream>>>((const float*)Pbuf, dinv, y, W1, b1, W2, gy, N);
    k_agg2 <<<gAgg, AT,     0, stream>>>(packed, G, gy, (float*)Pbuf, E, nbkt);
    k_node3<<<gN,   256,    0, stream>>>((const float*)Pbuf, dinv, gy, b2, (float2*)d_out, N);
}